// Round 7
// baseline (668.118 us; speedup 1.0000x reference)
//
#include <hip/hip_runtime.h>

#define T_STEPS 1000
#define NB 256
#define DZ 64
#define DH 256
#define DS 16
#define CHUNK 64
#define NCHUNK 16   // 15 full chunks of 64 + last chunk of 40 = exactly 1000 steps

// LDS-only barrier: drains lgkmcnt (LDS ordering) but NOT vmcnt.
// Safe: global loads land in private regs; global stores are never read back.
__device__ __forceinline__ void barrier_lgkm() {
    asm volatile("s_waitcnt lgkmcnt(0)\n\ts_barrier" ::: "memory");
}

// DPP cross-lane move / add (VALU pipe, no LDS traffic).
// 0xB1 = quad_perm[1,0,3,2] (xor1); 0x4E = quad_perm[2,3,0,1] (xor2);
// 0x124/0x128 = row_ror 4/8 (within each 16-lane row).
template<int CTRL>
__device__ __forceinline__ float dpp_mov(float x) {
    return __int_as_float(
        __builtin_amdgcn_update_dpp(0, __float_as_int(x), CTRL, 0xF, 0xF, true));
}
template<int CTRL>
__device__ __forceinline__ float dpp_add(float x) { return x + dpp_mov<CTRL>(x); }

// 4x4 quad transpose-reduce: p0..p3 are this lane's partials for outputs m=0..3.
// Result: lane (q = lane&3) holds sum over its 4-lane quad of p_q.
// 3 DPP + 3 adds + 6 cndmask (masks loop-invariant).
__device__ __forceinline__ float quad_transpose_sum(float p0, float p1, float p2,
                                                    float p3, bool b1, bool b2) {
    float rA = dpp_mov<0xB1>(b1 ? p0 : p1);
    float uA = (b1 ? p1 : p0) + rA;
    float rB = dpp_mov<0xB1>(b1 ? p2 : p3);
    float uB = (b1 ? p3 : p2) + rB;
    float rC = dpp_mov<0x4E>(b2 ? uA : uB);
    return (b2 ? uB : uA) + rC;
}

// One block per trial b; 1024 threads = 16 waves = 4 waves/SIMD.
// ROUND-13: cut LDS return bytes 4x. The 535us plateau is LDS-return-path bound:
// 132 B/lane/step (64B z + 64B za + 4B s) x 1024 lanes = 135 KB/step at 128 B/cy
// = ~1050 cy/step, matching measured 1284 with issue overlap. Bank conflicts = 0
// is a red herring (broadcast b128 still moves 1 KB/instr through data return).
// Restructure: each lane reads a 4-float slice (16B) reused across 4 outputs:
//  - Phase 1: 16-lane row owns 4 h's (h = 4*(tid>>4)+m); lane r4 reads
//    z[4r4..4r4+4), 16 FMA -> 4 partials; quad transpose-reduce + ror4 + ror8
//    -> every lane holds full dot for h = 4g+(lane&3). r4<4 lanes write za_sh.
//  - Phase 2: wave owns 4 j's (j = 4w+m); lane l reads za[4l..4l+4), 16 FMA;
//    transpose + C*s/h2 fold + ror4 + ror8 + xor16 (ds_swizzle) + xor32
//    (ds_bpermute) -> all lanes hold z_new[4w+(l&3)]. l<4 write z_sh + out.
// LDS traffic drops to ~44 B/lane/step; VALU rises ~55->~84 instr (still the
// 32 MAC/lane floor + deeper reduce). Summation tree changes; round-4's
// different tree also measured absmax 0.25 (threshold 0.925).
__global__ __launch_bounds__(1024)
__attribute__((amdgpu_waves_per_eu(4, 4)))
void plrnn_scan(const float* __restrict__ z0, const float* __restrict__ s,
                const float* __restrict__ A,  const float* __restrict__ W1,
                const float* __restrict__ W2, const float* __restrict__ h1,
                const float* __restrict__ h2, const float* __restrict__ C,
                float* __restrict__ out)
{
    const int tid = threadIdx.x;
    const int b   = blockIdx.x;
    const int qq  = tid & 3;             // m-index within quad
    const bool b1 = (tid & 1) != 0;      // transpose select masks (loop-invariant)
    const bool b2 = (tid & 2) != 0;
    const int r4  = tid & 15;            // row position (phase-1 z slice)
    const int g1  = tid >> 4;            // phase-1 h-group: h = 4*g1 + m
    const int wv  = tid >> 6;            // wave: phase-2 j-group: j = 4*wv + m
    const int l   = tid & 63;            // lane (phase-2 za slice)
    const int d   = (tid >> 2) & 15;     // phase-2 s-component

    __shared__ __align__(16) float z_sh[DZ];
    __shared__ __align__(16) float za_sh[DH];         // dense, no skew needed
    __shared__ __align__(16) float s_sh[CHUNK * DS];  // 64 steps of s[t][b][0..15]

    // ---- loop-invariant weights (32 floats + C scalar) ----
    float4 w1v[4];    // w1v[m] = W1[b][4*g1+m][4*r4 .. +4)
    {
        const float* base = W1 + (size_t)b * DH * DZ + 4 * r4;
        #pragma unroll
        for (int m = 0; m < 4; ++m)
            w1v[m] = *(const float4*)(base + (size_t)(4 * g1 + m) * DZ);
    }
    float4 w2v[4];    // w2v[m] = W2[b][4*wv+m][4*l .. +4)
    {
        const float* base = W2 + (size_t)b * DZ * DH + 4 * l;
        #pragma unroll
        for (int m = 0; m < 4; ++m)
            w2v[m] = *(const float4*)(base + (size_t)(4 * wv + m) * DH);
    }

    // med3-relu constants for h = 4*g1 + qq: za = med3(sgn*p + off, lo, hi)
    const int   hsel = 4 * g1 + qq;
    const float h1r  = h1[hsel];
    const float rsgn = (h1r > 0.f) ?  1.f : -1.f;
    const float roff = (h1r > 0.f) ?  h1r :  0.f;
    const float rlo  = fminf(h1r, 0.f);
    const float rhi  = fmaxf(h1r, 0.f);

    // phase-2 constants for j = 4*wv + qq
    const int   jsel  = 4 * wv + qq;
    const float Aj    = A[jsel];
    const float h2j16 = h2[jsel] * 0.0625f;   // h2/16: 16 post-transpose copies summed
    const float cj    = C[jsel * DS + d];     // C[j][d], d = (tid>>2)&15
    float zr = z0[b * DZ + jsel];             // z state (replicated across the 16 copies)

    const int bpi = (l ^ 32) << 2;            // ds_bpermute byte index for xor32

    if (tid < DZ) z_sh[tid] = z0[b * DZ + tid];

    // s prefetch: thread tid holds s[t0+srow][b][scol] for the NEXT chunk
    const int srow = tid >> 4, scol = tid & 15;
    float sreg = s[(size_t)min(srow, T_STEPS - 1) * NB * DS + (size_t)b * DS + scol];

    float* outp = out + (size_t)b * DZ + jsel;    // valid for the l<4 store lanes

    __syncthreads();

    for (int ci = 0; ci < NCHUNK; ++ci) {
        const int t0 = ci * CHUNK;
        const int nt = (ci == NCHUNK - 1) ? (T_STEPS - t0) : CHUNK;   // 64 or 40
        s_sh[tid] = sreg;                 // visible after this step's barrier A
        {
            int tl = min(t0 + CHUNK + srow, T_STEPS - 1);
            sreg = s[(size_t)tl * NB * DS + (size_t)b * DS + scol];
        }

        #pragma unroll 4
        for (int tt = 0; tt < nt; ++tt) {
            // ---- phase 1: 4 partial dots from a 16B z slice ----
            float4 zv = *(const float4*)(z_sh + 4 * r4);
            float a0 = w1v[0].x * zv.x, a1 = w1v[1].x * zv.x,
                  a2 = w1v[2].x * zv.x, a3 = w1v[3].x * zv.x;
            a0 = fmaf(w1v[0].y, zv.y, a0); a1 = fmaf(w1v[1].y, zv.y, a1);
            a2 = fmaf(w1v[2].y, zv.y, a2); a3 = fmaf(w1v[3].y, zv.y, a3);
            a0 = fmaf(w1v[0].z, zv.z, a0); a1 = fmaf(w1v[1].z, zv.z, a1);
            a2 = fmaf(w1v[2].z, zv.z, a2); a3 = fmaf(w1v[3].z, zv.z, a3);
            a0 = fmaf(w1v[0].w, zv.w, a0); a1 = fmaf(w1v[1].w, zv.w, a1);
            a2 = fmaf(w1v[2].w, zv.w, a2); a3 = fmaf(w1v[3].w, zv.w, a3);
            float t1 = quad_transpose_sum(a0, a1, a2, a3, b1, b2);
            t1 = dpp_add<0x124>(t1);      // += ror4
            t1 = dpp_add<0x128>(t1);      // += ror8  -> full 64-z dot for h=4g1+qq
            float za = __builtin_amdgcn_fmed3f(fmaf(rsgn, t1, roff), rlo, rhi);
            if (r4 < 4) za_sh[4 * g1 + r4] = za;   // r4<4 => qq==r4
            barrier_lgkm();               // A: za_sh (+ s_sh at chunk start) visible

            // ---- phase 2: 4 partial dots from a 16B za slice ----
            float4 av = *(const float4*)(za_sh + 4 * l);
            float sv = s_sh[tt * DS + d];
            float p0 = w2v[0].x * av.x, p1 = w2v[1].x * av.x,
                  p2 = w2v[2].x * av.x, p3 = w2v[3].x * av.x;
            p0 = fmaf(w2v[0].y, av.y, p0); p1 = fmaf(w2v[1].y, av.y, p1);
            p2 = fmaf(w2v[2].y, av.y, p2); p3 = fmaf(w2v[3].y, av.y, p3);
            p0 = fmaf(w2v[0].z, av.z, p0); p1 = fmaf(w2v[1].z, av.z, p1);
            p2 = fmaf(w2v[2].z, av.z, p2); p3 = fmaf(w2v[3].z, av.z, p3);
            p0 = fmaf(w2v[0].w, av.w, p0); p1 = fmaf(w2v[1].w, av.w, p1);
            p2 = fmaf(w2v[2].w, av.w, p2); p3 = fmaf(w2v[3].w, av.w, p3);
            float pm = quad_transpose_sum(p0, p1, p2, p3, b1, b2);
            pm += fmaf(cj, sv, h2j16);    // fold C[j,d]*s_t[d] + h2/16 (16 copies sum)
            pm = dpp_add<0x124>(pm);      // += ror4
            pm = dpp_add<0x128>(pm);      // += ror8   (row's 4 quads)
            pm += __int_as_float(__builtin_amdgcn_ds_swizzle(
                      __float_as_int(pm), 0x401F));            // += lane^16
            pm += __int_as_float(__builtin_amdgcn_ds_bpermute(
                      bpi, __float_as_int(pm)));               // += lane^32
            float zn = fmaf(Aj, zr, pm);  // z_new[4*wv + (l&3)] in every lane
            zr = zn;
            if (l < 4) {                  // l<4 => qq==l: writes j = 4*wv + l
                z_sh[4 * wv + l] = zn;
                *outp = zn;
            }
            outp += NB * DZ;
            barrier_lgkm();               // B: z_sh update visible for next phase 1
        }
    }
}

extern "C" void kernel_launch(void* const* d_in, const int* in_sizes, int n_in,
                              void* d_out, int out_size, void* d_ws, size_t ws_size,
                              hipStream_t stream) {
    const float* z0p = (const float*)d_in[0];
    const float* sp  = (const float*)d_in[1];
    const float* Ap  = (const float*)d_in[2];
    const float* W1p = (const float*)d_in[3];
    const float* W2p = (const float*)d_in[4];
    const float* h1p = (const float*)d_in[5];
    const float* h2p = (const float*)d_in[6];
    const float* Cp  = (const float*)d_in[7];

    plrnn_scan<<<dim3(NB), dim3(1024), 0, stream>>>(z0p, sp, Ap, W1p, W2p, h1p, h2p, Cp,
                                                    (float*)d_out);
}

// Round 8
// 571.390 us; speedup vs baseline: 1.1693x; 1.1693x over previous
//
#include <hip/hip_runtime.h>

#define T_STEPS 1000
#define NB 256
#define DZ 64
#define DH 256
#define DS 16
#define CHUNK 64
#define NCHUNK 16   // 15 full chunks of 64 + last chunk of 40 = exactly 1000 steps

// LDS-only barrier: drains lgkmcnt (LDS ordering) but NOT vmcnt.
// Safe: global loads land in private regs; global stores are never read back.
__device__ __forceinline__ void barrier_lgkm() {
    asm volatile("s_waitcnt lgkmcnt(0)\n\ts_barrier" ::: "memory");
}

// Packed fp32 pair + 16-byte pair-of-pairs (keeps ds_read_b128 loads).
typedef float fp2 __attribute__((ext_vector_type(2)));
struct __align__(16) fp2x2 { fp2 lo, hi; };

// v_pk_fma_f32: d = a*b + c on a float2 in ONE issue slot (VOP3P).
// The 157.3 TF fp32 spec rate IS this instruction; scalar v_fmac is half rate.
// Inline asm guarantees selection (non-volatile: scheduler may reorder freely).
__device__ __forceinline__ fp2 pk_fma(fp2 a, fp2 b, fp2 c) {
    fp2 d;
    asm("v_pk_fma_f32 %0, %1, %2, %3" : "=v"(d) : "v"(a), "v"(b), "v"(c));
    return d;
}

// VALU-pipe cross-lane add via DPP (fuses to v_add_f32_dpp).
// CTRL: 0xB1 = quad_perm[1,0,3,2] (xor1); 0x4E = quad_perm[2,3,0,1] (xor2);
//       0x121/0x122/0x124/0x128 = row_ror 1/2/4/8.
template<int CTRL>
__device__ __forceinline__ float dpp_add(float x) {
    int y = __builtin_amdgcn_update_dpp(0, __float_as_int(x), CTRL, 0xF, 0xF, true);
    return x + __int_as_float(y);
}
// Sum across the 16 lanes of a DPP row (every lane ends with the row total).
__device__ __forceinline__ float row16_allsum(float x) {
    x = dpp_add<0x128>(x);   // += ror8
    x = dpp_add<0x124>(x);   // += ror4
    x = dpp_add<0x122>(x);   // += ror2
    x = dpp_add<0x121>(x);   // += ror1
    return x;
}

// One block per trial b; 1024 threads = 16 waves = 4 waves/SIMD.
// ROUND-14: round-6 structure (measured best: 535us rocprof) with the MAC loops
// moved to v_pk_fma_f32. Round-7 falsified the LDS-bandwidth theory (cutting
// LDS bytes 4x while adding ~30 VALU/lane cost EXACTLY the issue model's
// +240 cy/step); the kernel is issue + lockstep-exchange bound. Packing halves
// the MAC issue count (32 scalar fma -> 16 pk_fma per lane per step),
// ~55 -> ~38 instr/lane. Everything else byte-identical to round-6:
//  - 2 LDS-only barriers/step (proved irreducible: atomics 3x worse),
//  - med3-relu, h2j/16 folded, skewed za_sh, register s-staging per chunk,
//  - exact 1000 steps (last chunk = 40).
__global__ __launch_bounds__(1024)
__attribute__((amdgpu_waves_per_eu(4, 4)))
void plrnn_scan(const float* __restrict__ z0, const float* __restrict__ s,
                const float* __restrict__ A,  const float* __restrict__ W1,
                const float* __restrict__ W2, const float* __restrict__ h1,
                const float* __restrict__ h2, const float* __restrict__ C,
                float* __restrict__ out)
{
    const int tid = threadIdx.x;
    const int b   = blockIdx.x;
    const int h   = tid >> 2;            // phase-1 hidden unit (quad-owned)
    const int q   = tid & 3;             // which 16-wide quarter of the W1 dot
    const int j   = tid >> 4;            // phase-2 z output (row-owned), 0..63
    const int r4  = tid & 15;            // lane within row = 16-h slice

    __shared__ __align__(16) float z_sh[DZ];
    __shared__ __align__(16) float za_sh[320];        // skew: idx = h + (h>>4)*4
    __shared__ __align__(16) float s_sh[CHUNK * DS];  // 64 steps of s[t][b][0..15]

    // ---- loop-invariant weights (32 floats + C scalar), packed as fp2 pairs ----
    fp2x2 w1v[4];    // W1[b][h][16q .. +16)  == 16 consecutive floats at 16*tid
    {
        const fp2x2* p = (const fp2x2*)(W1 + (size_t)b * DH * DZ) + 4 * tid;
        #pragma unroll
        for (int k = 0; k < 4; ++k) w1v[k] = p[k];
    }
    fp2x2 w2v[4];    // W2[b][j][16*r4 .. +16) == 16 consecutive floats at 16*tid
    {
        const fp2x2* p = (const fp2x2*)(W2 + (size_t)b * DZ * DH) + 4 * tid;
        #pragma unroll
        for (int k = 0; k < 4; ++k) w2v[k] = p[k];
    }
    const float cj  = C[tid];             // C[j][r4]: DZ*DS == 1024 == blockDim

    // med3-relu constants: za = med3(sgn*p + off, lo, hi)
    const float h1r  = h1[h];
    const float rsgn = (h1r > 0.f) ?  1.f : -1.f;
    const float roff = (h1r > 0.f) ?  h1r :  0.f;
    const float rlo  = fminf(h1r, 0.f);
    const float rhi  = fmaxf(h1r, 0.f);

    const float Aj    = A[j];
    const float h2j16 = h2[j] * 0.0625f;  // h2[j]/16, folded into the reduce
    float zr = z0[b * DZ + j];            // z state for the row's j (replicated x16)

    if (tid < DZ) z_sh[tid] = z0[b * DZ + tid];

    // s prefetch: thread tid holds s[t0+srow][b][scol] for the NEXT chunk
    const int srow = tid >> 4, scol = tid & 15;
    float sreg = s[(size_t)min(srow, T_STEPS - 1) * NB * DS + (size_t)b * DS + scol];

    const int zi = h + ((h >> 4) << 2);   // skewed za_sh index for phase-1 store
    float* outp = out + (size_t)b * DZ + j;   // advanced by NB*DZ per step

    __syncthreads();

    for (int ci = 0; ci < NCHUNK; ++ci) {
        const int t0 = ci * CHUNK;
        const int nt = (ci == NCHUNK - 1) ? (T_STEPS - t0) : CHUNK;   // 64 or 40
        s_sh[tid] = sreg;                 // visible after this step's barrier A
        {
            int tl = min(t0 + CHUNK + srow, T_STEPS - 1);
            sreg = s[(size_t)tl * NB * DS + (size_t)b * DS + scol];
        }

        #pragma unroll 4
        for (int tt = 0; tt < nt; ++tt) {
            // ---- phase 1: Wz[h] = W1 row · z (LDS b128 broadcast reads) ----
            const fp2x2* z2 = (const fp2x2*)(z_sh + 16 * q);
            fp2 ac0 = {0.f, 0.f}, ac1 = {0.f, 0.f};
            #pragma unroll
            for (int k = 0; k < 4; ++k) {
                fp2x2 zv = z2[k];
                ac0 = pk_fma(w1v[k].lo, zv.lo, ac0);
                ac1 = pk_fma(w1v[k].hi, zv.hi, ac1);
            }
            fp2 acs = ac0 + ac1;          // v_pk_add_f32
            float p1 = acs.x + acs.y;
            p1 = dpp_add<0xB1>(p1);       // quad butterfly: += lane^1
            p1 = dpp_add<0x4E>(p1);       //                 += lane^2
            float za = __builtin_amdgcn_fmed3f(fmaf(rsgn, p1, roff), rlo, rhi);
            if (q == 0) za_sh[zi] = za;
            barrier_lgkm();               // A: za_sh (+ s_sh at chunk start) visible

            // ---- phase 2: row computes z_new[j] over full h ----
            const fp2x2* q4 = (const fp2x2*)(za_sh + 20 * r4);  // skewed 16-slice
            float sv = s_sh[tt * DS + r4];                      // this lane's s elem
            fp2 pc0 = {0.f, 0.f}, pc1 = {0.f, 0.f};
            #pragma unroll
            for (int k = 0; k < 4; ++k) {
                fp2x2 v = q4[k];
                pc0 = pk_fma(w2v[k].lo, v.lo, pc0);
                pc1 = pk_fma(w2v[k].hi, v.hi, pc1);
            }
            fp2 pcs = pc0 + pc1;          // v_pk_add_f32
            float pa = (pcs.x + pcs.y) + fmaf(cj, sv, h2j16);   // fold C·s + h2/16
            pa = row16_allsum(pa);        // VALU DPP rotation reduce (no LDS)

            // ---- epilogue: every lane of the row holds the full sum ----
            float zn = fmaf(Aj, zr, pa);
            zr = zn;
            if (r4 == 0) {
                z_sh[j] = zn;
                *outp = zn;               // every computed step is a real step
            }
            outp += NB * DZ;
            barrier_lgkm();               // B: z_sh update visible for next phase 1
        }
    }
}

extern "C" void kernel_launch(void* const* d_in, const int* in_sizes, int n_in,
                              void* d_out, int out_size, void* d_ws, size_t ws_size,
                              hipStream_t stream) {
    const float* z0p = (const float*)d_in[0];
    const float* sp  = (const float*)d_in[1];
    const float* Ap  = (const float*)d_in[2];
    const float* W1p = (const float*)d_in[3];
    const float* W2p = (const float*)d_in[4];
    const float* h1p = (const float*)d_in[5];
    const float* h2p = (const float*)d_in[6];
    const float* Cp  = (const float*)d_in[7];

    plrnn_scan<<<dim3(NB), dim3(1024), 0, stream>>>(z0p, sp, Ap, W1p, W2p, h1p, h2p, Cp,
                                                    (float*)d_out);
}